// Round 1
// baseline (500.654 us; speedup 1.0000x reference)
//
#include <hip/hip_runtime.h>

#define NB    8192
#define NEI   64
#define DIM   128
#define D2    256
#define NR_W  1001   // 2*CNT_R+1
#define NR_Z  1000   // 2*CNT_R
#define EP_LD 132    // padded LDS row stride for ep (f32), %4==0, breaks bank aliasing

// ---------------- precompute kernels ----------------

// normalized hyperplane table: norm_t[r][k] = w_r_table[r][k] / ||w_r_table[r]||
__global__ void k_norm(const float* __restrict__ w_r_table, float* __restrict__ norm_t) {
    int r = blockIdx.x;          // 0..1000
    int t = threadIdx.x;         // 0..127
    float v = w_r_table[r * DIM + t];
    float s = v * v;
    #pragma unroll
    for (int m = 1; m < 64; m <<= 1) s += __shfl_xor(s, m);
    __shared__ float sh[2];
    if ((t & 63) == 0) sh[t >> 6] = s;
    __syncthreads();
    float tot = sh[0] + sh[1];
    norm_t[r * DIM + t] = v / sqrtf(tot);
}

// Tq[r][o] = attn_W_b[o] + sum_k attn_W_w[o][k] * zq_table[r][k]   (k < 128)
__global__ void k_tq(const float* __restrict__ zq_table, const float* __restrict__ W,
                     const float* __restrict__ bias, float* __restrict__ tq_t) {
    int r = blockIdx.x;          // 0..999
    int o = threadIdx.x;         // 0..255
    __shared__ float z[DIM];
    if (o < DIM) z[o] = zq_table[r * DIM + o];
    __syncthreads();
    float acc = bias[o];
    #pragma unroll 8
    for (int k = 0; k < DIM; ++k) acc += W[o * D2 + k] * z[k];
    tq_t[r * D2 + o] = acc;
}

// w2t[k][o] = attn_W_w[o][128+k]  (transposed second half, for coalesced GEMM B reads)
__global__ void k_w2t(const float* __restrict__ W, float* __restrict__ w2t) {
    int k = blockIdx.x;          // 0..127
    int o = threadIdx.x;         // 0..255
    w2t[k * D2 + o] = W[o * D2 + DIM + k];
}

// ---------------- main fused kernel: one block per b ----------------

__global__ __launch_bounds__(256) void k_main(
    const float* __restrict__ e_emb,    // (B,64,128)
    const float* __restrict__ rw,       // (B,64)
    const int*   __restrict__ nei_rid,  // (B,64)
    const int*   __restrict__ q_rid,    // (B,)
    const float* __restrict__ norm_t,   // (1001,128)
    const float* __restrict__ tq_t,     // (1000,256)
    const float* __restrict__ w2t,      // (128,256)
    const float* __restrict__ u_a_w,    // (256,)
    float* __restrict__ out)            // (B,64)
{
    __shared__ float ep[NEI * EP_LD];   // 33792 B
    __shared__ float w2c[16 * D2];      // 16384 B (16-k chunk of w2t)
    __shared__ float tqs[D2];
    __shared__ float uas[D2];
    __shared__ float alp[NEI];
    __shared__ int   rids[NEI];

    const int b = blockIdx.x;
    const int t = threadIdx.x;

    // stage Tq row, u_a, rids
    {
        int qr = q_rid[b];
        tqs[t] = tq_t[qr * D2 + t];
        uas[t] = u_a_w[t];
        if (t < NEI) rids[t] = nei_rid[b * NEI + t];
    }
    // stage e coalesced (float4) into padded LDS tile
    {
        const float4* src = (const float4*)(e_emb + (size_t)b * NEI * DIM);
        #pragma unroll
        for (int i = 0; i < 8; ++i) {
            int g = t + 256 * i;            // float4 index 0..2047
            float4 v = src[g];
            int f = g * 4;
            int n = f >> 7, k = f & 127;
            *(float4*)&ep[n * EP_LD + k] = v;
        }
    }
    __syncthreads();

    // hyperplane projection in place: 64 rows x 4 threads each
    {
        int n = t >> 2, j = t & 3;
        int rid = rids[n];
        const float4* nr = (const float4*)(norm_t + rid * DIM + j * 32);
        float4 nv[8];
        float part = 0.f;
        #pragma unroll
        for (int i = 0; i < 8; ++i) {
            nv[i] = nr[i];
            float4 ev = *(float4*)&ep[n * EP_LD + j * 32 + i * 4];
            part += ev.x * nv[i].x + ev.y * nv[i].y + ev.z * nv[i].z + ev.w * nv[i].w;
        }
        part += __shfl_xor(part, 1);
        part += __shfl_xor(part, 2);
        float d = part;                     // e . n  (full row dot)
        #pragma unroll
        for (int i = 0; i < 8; ++i) {
            float4* p = (float4*)&ep[n * EP_LD + j * 32 + i * 4];
            float4 ev = *p;
            ev.x -= d * nv[i].x; ev.y -= d * nv[i].y;
            ev.z -= d * nv[i].z; ev.w -= d * nv[i].w;
            *p = ev;
        }
    }

    // GEMM: v[n][o] = sum_k ep[n][k] * w2t[k][o]; thread tile: rows ty*4+i, cols tx*4+64j+l
    const int tx = t & 15, ty = t >> 4;
    float acc[4][16];
    #pragma unroll
    for (int i = 0; i < 4; ++i)
        #pragma unroll
        for (int j = 0; j < 16; ++j) acc[i][j] = 0.f;

    for (int c = 0; c < 8; ++c) {           // 16-k chunks
        __syncthreads();                    // also fences projection writes on c==0
        {
            const float4* src = (const float4*)(w2t + c * 16 * D2);
            float4* dst = (float4*)w2c;
            #pragma unroll
            for (int i = 0; i < 4; ++i) dst[t + 256 * i] = src[t + 256 * i];
        }
        __syncthreads();
        #pragma unroll
        for (int kk = 0; kk < 16; kk += 4) {
            float4 a[4];
            #pragma unroll
            for (int i = 0; i < 4; ++i)
                a[i] = *(const float4*)&ep[(ty * 4 + i) * EP_LD + c * 16 + kk];
            #pragma unroll
            for (int kq = 0; kq < 4; ++kq) {
                float4 bv[4];
                #pragma unroll
                for (int j = 0; j < 4; ++j)
                    bv[j] = *(const float4*)&w2c[(kk + kq) * D2 + tx * 4 + 64 * j];
                #pragma unroll
                for (int i = 0; i < 4; ++i) {
                    float av = (kq == 0) ? a[i].x : (kq == 1) ? a[i].y : (kq == 2) ? a[i].z : a[i].w;
                    #pragma unroll
                    for (int j = 0; j < 4; ++j) {
                        acc[i][j * 4 + 0] += av * bv[j].x;
                        acc[i][j * 4 + 1] += av * bv[j].y;
                        acc[i][j * 4 + 2] += av * bv[j].z;
                        acc[i][j * 4 + 3] += av * bv[j].w;
                    }
                }
            }
        }
    }

    // epilogue: tanh + dot with u_a, reduce across the 16 tx lanes
    float part[4] = {0.f, 0.f, 0.f, 0.f};
    #pragma unroll
    for (int i = 0; i < 4; ++i)
        #pragma unroll
        for (int j = 0; j < 4; ++j)
            #pragma unroll
            for (int l = 0; l < 4; ++l) {
                int o = tx * 4 + 64 * j + l;
                float v = acc[i][j * 4 + l] + tqs[o];
                float t2 = __expf(2.f * v);          // tanh(v) = 1 - 2/(e^{2v}+1)
                float h = 1.f - 2.f / (t2 + 1.f);
                part[i] += uas[o] * h;
            }
    #pragma unroll
    for (int m = 1; m < 16; m <<= 1) {
        #pragma unroll
        for (int i = 0; i < 4; ++i) part[i] += __shfl_xor(part[i], m);
    }
    if (tx == 0) {
        #pragma unroll
        for (int i = 0; i < 4; ++i) alp[ty * 4 + i] = part[i];
    }
    __syncthreads();

    // softmax over 64 neighbors + rw   (u_a_b cancels in softmax)
    if (t < NEI) {
        float a = alp[t];
        float mx = a;
        #pragma unroll
        for (int m = 1; m < 64; m <<= 1) mx = fmaxf(mx, __shfl_xor(mx, m));
        float p = __expf(a - mx);
        float s = p;
        #pragma unroll
        for (int m = 1; m < 64; m <<= 1) s += __shfl_xor(s, m);
        out[b * NEI + t] = p / s + rw[b * NEI + t];
    }
}

// ---------------- launch ----------------

extern "C" void kernel_launch(void* const* d_in, const int* in_sizes, int n_in,
                              void* d_out, int out_size, void* d_ws, size_t ws_size,
                              hipStream_t stream) {
    const float* e_emb   = (const float*)d_in[0];
    const float* rw      = (const float*)d_in[1];
    const float* w_r_tab = (const float*)d_in[2];
    const float* zq_tab  = (const float*)d_in[3];
    const float* attn_W  = (const float*)d_in[4];
    const float* attn_b  = (const float*)d_in[5];
    const float* u_a_w   = (const float*)d_in[6];
    // d_in[7] = u_a_b: cancels in softmax, unused
    const int*   nei_rid = (const int*)d_in[8];
    const int*   q_rid   = (const int*)d_in[9];
    float* out = (float*)d_out;

    float* ws = (float*)d_ws;
    float* norm_t = ws;                          // 1001*128
    float* tq_t   = norm_t + NR_W * DIM;         // 1000*256
    float* w2t    = tq_t + NR_Z * D2;            // 128*256

    k_norm<<<NR_W, DIM, 0, stream>>>(w_r_tab, norm_t);
    k_tq<<<NR_Z, D2, 0, stream>>>(zq_tab, attn_W, attn_b, tq_t);
    k_w2t<<<DIM, D2, 0, stream>>>(attn_W, w2t);
    k_main<<<NB, 256, 0, stream>>>(e_emb, rw, nei_rid, q_rid,
                                   norm_t, tq_t, w2t, u_a_w, out);
}

// Round 2
// 147.853 us; speedup vs baseline: 3.3862x; 3.3862x over previous
//
#include <hip/hip_runtime.h>

#define NB    8192
#define NEI   64
#define DIM   128
#define D2    256
#define NR_W  1001   // 2*CNT_R+1
#define NR_Z  1000   // 2*CNT_R
#define EPB_LD 136   // bf16 elems per LDS row (128 + 8 pad) -> bank step 4/row, ~2-way

typedef __attribute__((ext_vector_type(8))) short bf16x8;   // 8 bf16 = 4 VGPR
typedef __attribute__((ext_vector_type(4))) float f32x4;

__device__ __forceinline__ ushort f2bf(float x) {
    union { float f; unsigned u; } c; c.f = x;
    unsigned u = c.u;
    return (ushort)((u + 0x7fffu + ((u >> 16) & 1u)) >> 16);   // RNE
}

// ---------------- precompute kernels ----------------

// normalized hyperplane table: norm_t[r][k] = w_r_table[r][k] / ||w_r_table[r]||
__global__ void k_norm(const float* __restrict__ w_r_table, float* __restrict__ norm_t) {
    int r = blockIdx.x;          // 0..1000
    int t = threadIdx.x;         // 0..127
    float v = w_r_table[r * DIM + t];
    float s = v * v;
    #pragma unroll
    for (int m = 1; m < 64; m <<= 1) s += __shfl_xor(s, m);
    __shared__ float sh[2];
    if ((t & 63) == 0) sh[t >> 6] = s;
    __syncthreads();
    float tot = sh[0] + sh[1];
    norm_t[r * DIM + t] = v / sqrtf(tot);
}

// Tq[r][o] = attn_W_b[o] + sum_{k<128} attn_W_w[o][k] * zq_table[r][k]
__global__ void k_tq(const float* __restrict__ zq_table, const float* __restrict__ W,
                     const float* __restrict__ bias, float* __restrict__ tq_t) {
    int r = blockIdx.x;          // 0..999
    int o = threadIdx.x;         // 0..255
    __shared__ float4 z4[32];
    if (o < 32) z4[o] = ((const float4*)(zq_table + r * DIM))[o];
    __syncthreads();
    const float4* wr = (const float4*)(W + o * D2);
    float acc = bias[o];
    #pragma unroll 8
    for (int i = 0; i < 32; ++i) {
        float4 wv = wr[i], zv = z4[i];
        acc += wv.x*zv.x + wv.y*zv.y + wv.z*zv.z + wv.w*zv.w;
    }
    tq_t[r * D2 + o] = acc;
}

// B fragments in mfma_16x16x32_bf16 order:
// bfrag[((nt*4+kt)*64 + lane)*8 + j] = W2[k][o], o = nt*16+(lane&15), k = kt*32+(lane>>4)*8+j
// where W2[k][o] = attn_W_w[o*256 + 128 + k]
__global__ void k_bfrag(const float* __restrict__ W, ushort* __restrict__ bfrag) {
    int nt = blockIdx.x;         // 0..15
    int kt = blockIdx.y;         // 0..3
    int l  = threadIdx.x;        // 0..63
    int o  = nt * 16 + (l & 15);
    int k  = kt * 32 + (l >> 4) * 8;
    const float4* src = (const float4*)(W + o * D2 + DIM + k);
    float4 a = src[0], c = src[1];
    uint4 w;
    w.x = f2bf(a.x) | ((unsigned)f2bf(a.y) << 16);
    w.y = f2bf(a.z) | ((unsigned)f2bf(a.w) << 16);
    w.z = f2bf(c.x) | ((unsigned)f2bf(c.y) << 16);
    w.w = f2bf(c.z) | ((unsigned)f2bf(c.w) << 16);
    *(uint4*)(bfrag + ((nt * 4 + kt) * 64 + l) * 8) = w;
}

// ---------------- main fused kernel: one block per b ----------------

__global__ __launch_bounds__(256) void k_main(
    const float* __restrict__ e_emb,    // (B,64,128)
    const float* __restrict__ rw,       // (B,64)
    const int*   __restrict__ nei_rid,  // (B,64)
    const int*   __restrict__ q_rid,    // (B,)
    const float* __restrict__ norm_t,   // (1001,128)
    const float* __restrict__ tq_t,     // (1000,256)
    const ushort* __restrict__ bfrag,   // (16,4,64,8) bf16
    const float* __restrict__ u_a_w,    // (256,)
    float* __restrict__ out)            // (B,64)
{
    __shared__ ushort ep16[NEI * EPB_LD];   // 17408 B
    __shared__ float  alpw[4][NEI];         // 1024 B

    const int b = blockIdx.x;
    const int t = threadIdx.x;
    const int wave = t >> 6, lane = t & 63;

    // ---- load e rows (4 lanes/row), project in registers, convert to bf16 LDS ----
    {
        const int row = t >> 2, q = t & 3;
        const float4* esrc = (const float4*)(e_emb + (size_t)b * NEI * DIM + row * DIM + q * 32);
        const int rid = nei_rid[b * NEI + row];
        const float4* nsrc = (const float4*)(norm_t + rid * DIM + q * 32);
        float4 ev[8], nv[8];
        #pragma unroll
        for (int i = 0; i < 8; ++i) { ev[i] = esrc[i]; nv[i] = nsrc[i]; }
        float part = 0.f;
        #pragma unroll
        for (int i = 0; i < 8; ++i)
            part += ev[i].x*nv[i].x + ev[i].y*nv[i].y + ev[i].z*nv[i].z + ev[i].w*nv[i].w;
        part += __shfl_xor(part, 1);
        part += __shfl_xor(part, 2);
        const float d = part;               // full-row e . n
        #pragma unroll
        for (int i = 0; i < 8; ++i) {
            ev[i].x -= d*nv[i].x; ev[i].y -= d*nv[i].y;
            ev[i].z -= d*nv[i].z; ev[i].w -= d*nv[i].w;
        }
        ushort* dst = &ep16[row * EPB_LD + q * 32];
        #pragma unroll
        for (int g = 0; g < 4; ++g) {
            float4 lo = ev[g*2], hi4 = ev[g*2+1];
            uint4 w;
            w.x = f2bf(lo.x)  | ((unsigned)f2bf(lo.y)  << 16);
            w.y = f2bf(lo.z)  | ((unsigned)f2bf(lo.w)  << 16);
            w.z = f2bf(hi4.x) | ((unsigned)f2bf(hi4.y) << 16);
            w.w = f2bf(hi4.z) | ((unsigned)f2bf(hi4.w) << 16);
            *(uint4*)(dst + g * 8) = w;
        }
    }

    // per-lane epilogue constants: o = wave*64 + nt*16 + (lane&15)
    const int ln = lane & 15, hi = lane >> 4;
    const int qr = q_rid[b];
    float tq4[4], ua4[4];
    #pragma unroll
    for (int nt = 0; nt < 4; ++nt) {
        int o = wave * 64 + nt * 16 + ln;
        tq4[nt] = tq_t[qr * D2 + o];
        ua4[nt] = u_a_w[o];
    }

    // B fragments for this wave's 64 output cols: 16 x bf16x8 (held in regs)
    bf16x8 bfr_[4][4];
    #pragma unroll
    for (int nt = 0; nt < 4; ++nt)
        #pragma unroll
        for (int kt = 0; kt < 4; ++kt)
            bfr_[nt][kt] = *(const bf16x8*)(bfrag + (((wave*4 + nt)*4 + kt)*64 + lane)*8);

    __syncthreads();

    // GEMM (waves split N; each wave does all 4 M-tiles) + fused epilogue per M-tile
    #pragma unroll
    for (int mt = 0; mt < 4; ++mt) {
        bf16x8 a_[4];
        #pragma unroll
        for (int kt = 0; kt < 4; ++kt)
            a_[kt] = *(const bf16x8*)&ep16[(mt*16 + ln) * EPB_LD + kt*32 + hi*8];
        f32x4 acc[4];
        #pragma unroll
        for (int nt = 0; nt < 4; ++nt) acc[nt] = (f32x4){0.f, 0.f, 0.f, 0.f};
        #pragma unroll
        for (int kt = 0; kt < 4; ++kt)
            #pragma unroll
            for (int nt = 0; nt < 4; ++nt)
                acc[nt] = __builtin_amdgcn_mfma_f32_16x16x32_bf16(a_[kt], bfr_[nt][kt], acc[nt], 0, 0, 0);
        // tanh + u_a dot; C/D layout: col = lane&15, row = mt*16 + (lane>>4)*4 + j
        float pr[4] = {0.f, 0.f, 0.f, 0.f};
        #pragma unroll
        for (int nt = 0; nt < 4; ++nt)
            #pragma unroll
            for (int j = 0; j < 4; ++j) {
                float v = acc[nt][j] + tq4[nt];
                float e2 = __expf(2.f * v);          // tanh(v) = 1 - 2/(e^{2v}+1)
                float h = 1.f - 2.f / (e2 + 1.f);
                pr[j] += ua4[nt] * h;
            }
        #pragma unroll
        for (int m = 1; m < 16; m <<= 1)
            #pragma unroll
            for (int j = 0; j < 4; ++j) pr[j] += __shfl_xor(pr[j], m);
        if (ln == 0) {
            #pragma unroll
            for (int j = 0; j < 4; ++j) alpw[wave][mt*16 + hi*4 + j] = pr[j];
        }
    }
    __syncthreads();

    // softmax over 64 neighbors + rw   (u_a_b cancels in softmax)
    if (t < NEI) {
        float a = alpw[0][t] + alpw[1][t] + alpw[2][t] + alpw[3][t];
        float mx = a;
        #pragma unroll
        for (int m = 1; m < 64; m <<= 1) mx = fmaxf(mx, __shfl_xor(mx, m));
        float p = __expf(a - mx);
        float s = p;
        #pragma unroll
        for (int m = 1; m < 64; m <<= 1) s += __shfl_xor(s, m);
        out[b * NEI + t] = p / s + rw[b * NEI + t];
    }
}

// ---------------- launch ----------------

extern "C" void kernel_launch(void* const* d_in, const int* in_sizes, int n_in,
                              void* d_out, int out_size, void* d_ws, size_t ws_size,
                              hipStream_t stream) {
    const float* e_emb   = (const float*)d_in[0];
    const float* rw      = (const float*)d_in[1];
    const float* w_r_tab = (const float*)d_in[2];
    const float* zq_tab  = (const float*)d_in[3];
    const float* attn_W  = (const float*)d_in[4];
    const float* attn_b  = (const float*)d_in[5];
    const float* u_a_w   = (const float*)d_in[6];
    // d_in[7] = u_a_b: cancels in softmax, unused
    const int*   nei_rid = (const int*)d_in[8];
    const int*   q_rid   = (const int*)d_in[9];
    float* out = (float*)d_out;

    float* ws = (float*)d_ws;
    float* norm_t = ws;                             // 1001*128 f32
    float* tq_t   = norm_t + NR_W * DIM;            // 1000*256 f32
    ushort* bfrag = (ushort*)(tq_t + NR_Z * D2);    // 16*4*64*8 bf16 (offset 16B-aligned)

    k_norm<<<NR_W, DIM, 0, stream>>>(w_r_tab, norm_t);
    k_tq<<<NR_Z, D2, 0, stream>>>(zq_tab, attn_W, attn_b, tq_t);
    k_bfrag<<<dim3(16, 4), 64, 0, stream>>>(attn_W, bfrag);
    k_main<<<NB, 256, 0, stream>>>(e_emb, rw, nei_rid, q_rid,
                                   norm_t, tq_t, bfrag, u_a_w, out);
}